// Round 14
// baseline (254.169 us; speedup 1.0000x reference)
//
#include <hip/hip_runtime.h>

typedef __attribute__((ext_vector_type(8))) __bf16 bf16x8;
typedef __attribute__((ext_vector_type(4))) float f32x4;
typedef __attribute__((ext_vector_type(16))) float f32x16;

#define NEG_BIG (-1e30f)

__device__ __forceinline__ unsigned short f2b(float f) {
    unsigned int u = __float_as_uint(f);
    u += 0x7FFFu + ((u >> 16) & 1u);
    return (unsigned short)(u >> 16);
}
__device__ __forceinline__ unsigned cvtpk(float lo, float hi) {
    unsigned r;
    asm("v_cvt_pk_bf16_f32 %0, %1, %2" : "=v"(r) : "v"(lo), "v"(hi));
    return r;
}

typedef const __attribute__((address_space(1))) unsigned int* gas_ptr;
typedef __attribute__((address_space(3))) unsigned int* las_ptr;
__device__ __forceinline__ void gload16(const void* g, void* l) {
    __builtin_amdgcn_global_load_lds((gas_ptr)g, (las_ptr)l, 16, 0, 0);
}

// ---------------- elementwise f32 -> bf16 (rn) ----------------
__global__ __launch_bounds__(256) void k_convert(
    const float* __restrict__ x, unsigned short* __restrict__ xb, int n4)
{
    int i = blockIdx.x * 256 + threadIdx.x;
    if (i >= n4) return;
    float4 v = reinterpret_cast<const float4*>(x)[i];
    ushort4 h;
    h.x = f2b(v.x); h.y = f2b(v.y); h.z = f2b(v.z); h.w = f2b(v.w);
    reinterpret_cast<ushort4*>(xb)[i] = h;
}

// ------------- W (K x N, f32) -> Wt (N x K) bf16 -------------
__global__ __launch_bounds__(256) void k_transpose(
    const float* __restrict__ W, unsigned short* __restrict__ Th, int K, int N)
{
    __shared__ float tile[64][65];
    const int n0 = blockIdx.x * 64, k0 = blockIdx.y * 64;
    const int c = threadIdx.x & 63, r0 = threadIdx.x >> 6;
    for (int rr = r0; rr < 64; rr += 4)
        tile[rr][c] = W[(size_t)(k0 + rr) * N + n0 + c];
    __syncthreads();
    for (int rr = r0; rr < 64; rr += 4)
        Th[(size_t)(n0 + rr) * K + k0 + c] = f2b(tile[c][rr]);
}

// ------------- plain bf16 GEMM: C = A * B^T(stored [N][K]) -------------
// BK=64, both-sides XOR swizzle (verified r13). Split epilogue.
__global__ __launch_bounds__(256) void k_gemm(
    const unsigned short* __restrict__ A, const unsigned short* __restrict__ B,
    void* __restrict__ CoutA, int NA, void* __restrict__ CoutB, int NB, int N1,
    const float* __restrict__ bias, int M, int K, int outF32)
{
    __shared__ __align__(16) unsigned short As[128][64];
    __shared__ __align__(16) unsigned short Bs[128][64];

    const int tid  = threadIdx.x;
    const int lane = tid & 63, wid = tid >> 6;
    const int wr = wid >> 1, wc = wid & 1;
    const int lrow = lane & 15, lko = (lane >> 4) << 3;
    const int bm = blockIdx.y, bn = blockIdx.x;

    const int srow = tid >> 3;                       // 0..31
    const int scol = ((tid & 7) ^ (srow & 7)) << 3;  // pre-swizzled k-offset
    const int wbase = wid * 1024;

    const int sw = (lrow & 7) << 3;
    const int c0 = lko ^ sw;
    const int c1 = (32 + lko) ^ sw;

    f32x4 acc[4][4] = {};

    const size_t aoff = (size_t)(bm * 128 + srow) * K + scol;
    const size_t boff = (size_t)(bn * 128 + srow) * K + scol;
    const size_t slab = (size_t)32 * K;

    for (int k0 = 0; k0 < K; k0 += 64) {
        #pragma unroll
        for (int s = 0; s < 4; ++s) {
            gload16(&A[aoff + s * slab + k0], (char*)&As[0][0] + s * 4096 + wbase);
            gload16(&B[boff + s * slab + k0], (char*)&Bs[0][0] + s * 4096 + wbase);
        }
        __syncthreads();

        #pragma unroll
        for (int kk2 = 0; kk2 < 2; ++kk2) {
            const int cc = kk2 ? c1 : c0;
            bf16x8 af[4], bf[4];
            #pragma unroll
            for (int m = 0; m < 4; ++m)
                af[m] = *reinterpret_cast<const bf16x8*>(&As[wr * 64 + m * 16 + lrow][cc]);
            #pragma unroll
            for (int n = 0; n < 4; ++n)
                bf[n] = *reinterpret_cast<const bf16x8*>(&Bs[wc * 64 + n * 16 + lrow][cc]);
            #pragma unroll
            for (int m = 0; m < 4; ++m)
                #pragma unroll
                for (int n = 0; n < 4; ++n)
                    acc[m][n] = __builtin_amdgcn_mfma_f32_16x16x32_bf16(af[m], bf[n], acc[m][n], 0, 0, 0);
        }
        __syncthreads();
    }

    const int rbase = bm * 128 + wr * 64 + ((lane >> 4) << 2);
    const int cbase = bn * 128 + wc * 64 + lrow;
    #pragma unroll
    for (int m = 0; m < 4; ++m)
        #pragma unroll
        for (int n = 0; n < 4; ++n) {
            const int col = cbase + n * 16;
            const float bv = bias ? bias[col] : 0.0f;
            const bool inA = (col < N1);
            const int ccol = inA ? col : (col - N1);
            const int cstr = inA ? NA : NB;
            void* base = inA ? CoutA : CoutB;
            #pragma unroll
            for (int r = 0; r < 4; ++r) {
                const size_t idx = (size_t)(rbase + m * 16 + r) * cstr + ccol;
                const float v = acc[m][n][r] + bv;
                if (outF32) ((float*)base)[idx] = v;
                else        ((unsigned short*)base)[idx] = f2b(v);
            }
        }
}

// ------------- fused causal GQA attention with ALiBi, 32x32 MFMA -------------
// block = (b, g, 32-row q-chunk), 4 waves = 4 q-heads; wave covers ALL 32
// q-rows of its head (halved LDS fragment traffic vs 16x16). Swapped QK^T
// (mfma(K,Q)): lane owns q-row (lane&31); in-lane softmax with ONE
// shfl_xor(32); P->A-frag via cvt_pk + shfl_xor(32) half-exchange (no P LDS).
// K: reg-staged, XOR ((key&15)<<3). V: gather-transposed [128][72].
__global__ __launch_bounds__(256, 2) void k_attn(
    const unsigned short* __restrict__ Qb,   // (B*T) x 2048 bf16
    const unsigned short* __restrict__ KVb,  // (B*T) x 1024 bf16 (k | v)
    unsigned short* __restrict__ AO)         // (B*T) x 2048 bf16
{
    __shared__ __align__(16) unsigned short Ksl[64][128]; // [key][dim ^ ((key&15)<<3)]
    __shared__ __align__(16) unsigned short Vt[128][72];  // [dim][key]

    const int blk = blockIdx.x;
    const int idx = blk >> 3;          // 0..63
    const int sub = blk & 7;
    const int b   = sub >> 2;
    const int g   = sub & 3;
    const int chunk = (idx < 32) ? (63 - idx) : (idx - 32);
    const int q0  = chunk * 32;

    const int tid = threadIdx.x;
    const int lane = tid & 63;
    const int w = tid >> 6;            // wave 0..3 = rep index
    const int h = w * 4 + g;           // query head
    const int ql = lane & 31;          // lane's q-col
    const int hb = lane >> 5;          // half (k-slot select)
    const float slope = exp2f(-0.5f * (float)(h + 1));
    const float isq = 0.088388347648318447f; // 1/sqrt(128)
    const int kswz = (ql & 15) << 3;   // K-read swizzle (row&15 == ql&15)

    // K staging (256 threads): 4 x uint4 per thread
    const int skey = tid >> 4;                 // 0..15
    const int sd0  = (tid & 15) << 3;
    // V staging (256 threads): 4 key-groups x 8 keys per thread
    const int vdim = tid & 127;
    const int vkg  = tid >> 7;                 // 0..1

    uint4 kreg[4];
    unsigned short vv[4][8];

    auto ldK = [&](int kb) {
        const int j0 = kb << 6;
        #pragma unroll
        for (int p = 0; p < 4; ++p) {
            const int key = skey + p * 16;
            kreg[p] = *reinterpret_cast<const uint4*>(
                &KVb[(size_t)(b * 2048 + j0 + key) * 1024 + g * 128 + sd0]);
        }
    };
    auto wrK = [&]() {
        #pragma unroll
        for (int p = 0; p < 4; ++p) {
            const int key = skey + p * 16;
            *reinterpret_cast<uint4*>(&Ksl[key][sd0 ^ ((key & 15) << 3)]) = kreg[p];
        }
    };
    auto ldV = [&](int kb) {
        const int j0 = kb << 6;
        #pragma unroll
        for (int gi = 0; gi < 4; ++gi) {
            const int kgi = gi * 2 + vkg;
            const size_t base = (size_t)(b * 2048 + j0 + kgi * 8) * 1024 + 512 + g * 128 + vdim;
            #pragma unroll
            for (int j = 0; j < 8; ++j)
                vv[gi][j] = KVb[base + (size_t)j * 1024];
        }
    };
    auto wrV = [&]() {
        #pragma unroll
        for (int gi = 0; gi < 4; ++gi) {
            const int kgi = gi * 2 + vkg;
            *reinterpret_cast<uint4*>(&Vt[vdim][kgi * 8]) =
                *reinterpret_cast<const uint4*>(&vv[gi][0]);
        }
    };

    // Q fragments: B[n=ql][k=8*hb+j] for 8 dim-slices
    bf16x8 qf[8];
    {
        const size_t qoff = (size_t)(b * 2048 + q0 + ql) * 2048 + h * 128 + 8 * hb;
        #pragma unroll
        for (int s = 0; s < 8; ++s)
            qf[s] = *reinterpret_cast<const bf16x8*>(&Qb[qoff + 16 * s]);
    }

    f32x16 oacc[4] = {};
    float mrow = NEG_BIG, lsum = 0.f;
    const int nkb = (q0 + 32 + 63) >> 6;
    const int q = q0 + ql;             // this lane's q-row

    // prologue: stage tile 0
    ldK(0); ldV(0);
    wrK(); wrV();
    __syncthreads();

    for (int kb = 0; kb < nkb; ++kb) {
        const int j0 = kb << 6;
        const bool pre = (kb + 1 < nkb);
        if (pre) { ldK(kb + 1); ldV(kb + 1); }

        // S^T[key][q] = K x Q^T : 64 keys x 32 q-rows
        f32x16 sa[2] = {};
        #pragma unroll
        for (int c = 0; c < 2; ++c) {
            const int krow = c * 32 + ql;
            #pragma unroll
            for (int s = 0; s < 8; ++s) {
                bf16x8 kf = *reinterpret_cast<const bf16x8*>(
                    &Ksl[krow][(16 * s + 8 * hb) ^ kswz]);
                sa[c] = __builtin_amdgcn_mfma_f32_32x32x16_bf16(kf, qf[s], sa[c], 0, 0, 0);
            }
        }

        // in-lane softmax: lane owns q-row q; 32 S-values in sa[2]
        float mt = NEG_BIG;
        #pragma unroll
        for (int c = 0; c < 2; ++c)
            #pragma unroll
            for (int r = 0; r < 16; ++r) {
                const int j = j0 + 32 * c + (r & 3) + 8 * (r >> 2) + 4 * hb;
                const float v = (j <= q) ? (sa[c][r] * isq + slope * (float)(j - q)) : NEG_BIG;
                sa[c][r] = v;
                mt = fmaxf(mt, v);
            }
        mt = fmaxf(mt, __shfl_xor(mt, 32));
        const float mn = fmaxf(mrow, mt);
        const float alpha = __expf(mrow - mn);
        mrow = mn;
        float ssum = 0.f;
        #pragma unroll
        for (int c = 0; c < 2; ++c)
            #pragma unroll
            for (int r = 0; r < 16; ++r) {
                const float pe = __expf(sa[c][r] - mn);
                sa[c][r] = pe;
                ssum += pe;
            }
        ssum += __shfl_xor(ssum, 32);
        lsum = lsum * alpha + ssum;

        // rescale accumulators: oacc reg r has q-row (r&3)+8*(r>>2)+4*hb
        float ar[16];
        #pragma unroll
        for (int r = 0; r < 16; ++r)
            ar[r] = __shfl(alpha, (r & 3) + 8 * (r >> 2) + 4 * hb);
        #pragma unroll
        for (int nb = 0; nb < 4; ++nb)
            #pragma unroll
            for (int r = 0; r < 16; ++r)
                oacc[nb][r] *= ar[r];

        // P -> bf16 A-frags via cvt_pk + half-exchange (keys ascending)
        unsigned pw[2][8];
        #pragma unroll
        for (int c = 0; c < 2; ++c)
            #pragma unroll
            for (int i = 0; i < 8; ++i)
                pw[c][i] = cvtpk(sa[c][2 * i], sa[c][2 * i + 1]);

        bf16x8 pA[4];
        #pragma unroll
        for (int s4 = 0; s4 < 4; ++s4) {
            const int half = s4 >> 1, a = 4 * (s4 & 1);
            const unsigned xw0 = hb ? pw[half][a]     : pw[half][a + 2];
            const unsigned xw1 = hb ? pw[half][a + 1] : pw[half][a + 3];
            const unsigned rx0 = (unsigned)__shfl_xor((int)xw0, 32);
            const unsigned rx1 = (unsigned)__shfl_xor((int)xw1, 32);
            union { unsigned u[4]; bf16x8 v; } f;
            f.u[0] = hb ? rx0 : pw[half][a];
            f.u[1] = hb ? rx1 : pw[half][a + 1];
            f.u[2] = hb ? pw[half][a + 2] : rx0;
            f.u[3] = hb ? pw[half][a + 3] : rx1;
            pA[s4] = f.v;
        }

        // PV: O[q][d] += P[q][k] * Vt[d][k]
        #pragma unroll
        for (int s4 = 0; s4 < 4; ++s4)
            #pragma unroll
            for (int nb = 0; nb < 4; ++nb) {
                bf16x8 vf = *reinterpret_cast<const bf16x8*>(
                    &Vt[nb * 32 + ql][16 * s4 + 8 * hb]);
                oacc[nb] = __builtin_amdgcn_mfma_f32_32x32x16_bf16(pA[s4], vf, oacc[nb], 0, 0, 0);
            }

        __syncthreads();             // all waves done reading Ksl/Vt
        if (pre) { wrK(); wrV(); }
        __syncthreads();             // next tile visible
    }

    // epilogue
    float lr[16];
    #pragma unroll
    for (int r = 0; r < 16; ++r)
        lr[r] = __shfl(lsum, (r & 3) + 8 * (r >> 2) + 4 * hb);
    #pragma unroll
    for (int nb = 0; nb < 4; ++nb)
        #pragma unroll
        for (int r = 0; r < 16; ++r) {
            const int row = q0 + (r & 3) + 8 * (r >> 2) + 4 * hb;
            const int col = h * 128 + nb * 32 + ql;
            AO[(size_t)(b * 2048 + row) * 2048 + col] = f2b(oacc[nb][r] / lr[r]);
        }
}

extern "C" void kernel_launch(void* const* d_in, const int* in_sizes, int n_in,
                              void* d_out, int out_size, void* d_ws, size_t ws_size,
                              hipStream_t stream)
{
    const float* x   = (const float*)d_in[0];  // (2,2048,2048)
    const float* Wq  = (const float*)d_in[1];  // (2048,2048)
    const float* Wkv = (const float*)d_in[2];  // (2048,1024)
    const float* Wo  = (const float*)d_in[3];  // (2048,2048)
    const float* bo  = (const float*)d_in[4];  // (2048,)

    char* ws = (char*)d_ws;
    unsigned short* xb  = (unsigned short*)(ws + (size_t)0);          // 16MB (later AO)
    unsigned short* Wt  = (unsigned short*)(ws + ((size_t)16 << 20)); // 12MB (3072x2048)
    unsigned short* Qb  = (unsigned short*)(ws + ((size_t)28 << 20)); // 16MB
    unsigned short* KVb = (unsigned short*)(ws + ((size_t)44 << 20)); // 8MB
    // total 52MB

    // x -> bf16
    k_convert<<<8192, 256, 0, stream>>>(x, xb, (2 * 2048 * 2048) / 4);

    // Wt rows 0..2047 = Wq^T, rows 2048..3071 = Wkv^T
    k_transpose<<<dim3(32, 32), 256, 0, stream>>>(Wq, Wt, 2048, 2048);
    k_transpose<<<dim3(16, 32), 256, 0, stream>>>(Wkv, Wt + (size_t)2048 * 2048, 2048, 1024);

    // fused QKV = x @ [Wq | Wkv]  (4096 x 3072 x 2048), split outputs
    k_gemm<<<dim3(24, 32), 256, 0, stream>>>(xb, Wt, Qb, 2048, KVb, 1024, 2048,
                                             nullptr, 4096, 2048, 0);

    // attention -> AO (reuses x buffer)
    k_attn<<<512, 256, 0, stream>>>(Qb, KVb, xb);

    // out = AO @ Wo + bo   (4096 x 2048 x 2048), f32 out
    k_transpose<<<dim3(32, 32), 256, 0, stream>>>(Wo, Wt, 2048, 2048);
    k_gemm<<<dim3(16, 32), 256, 0, stream>>>(xb, Wt, d_out, 2048, nullptr, 2048, 2048,
                                             bo, 4096, 2048, 1);
}

// Round 15
// 241.762 us; speedup vs baseline: 1.0513x; 1.0513x over previous
//
#include <hip/hip_runtime.h>

typedef __attribute__((ext_vector_type(8))) __bf16 bf16x8;
typedef __attribute__((ext_vector_type(4))) float f32x4;

#define NEG_BIG (-1e30f)

__device__ __forceinline__ unsigned short f2b(float f) {
    unsigned int u = __float_as_uint(f);
    u += 0x7FFFu + ((u >> 16) & 1u);
    return (unsigned short)(u >> 16);
}
__device__ __forceinline__ unsigned cvtpk(float lo, float hi) {
    unsigned r;
    asm("v_cvt_pk_bf16_f32 %0, %1, %2" : "=v"(r) : "v"(lo), "v"(hi));
    return r;
}

typedef const __attribute__((address_space(1))) unsigned int* gas_ptr;
typedef __attribute__((address_space(3))) unsigned int* las_ptr;
__device__ __forceinline__ void gload16(const void* g, void* l) {
    __builtin_amdgcn_global_load_lds((gas_ptr)g, (las_ptr)l, 16, 0, 0);
}

// ---------------- elementwise f32 -> bf16 (rn) ----------------
__global__ __launch_bounds__(256) void k_convert(
    const float* __restrict__ x, unsigned short* __restrict__ xb, int n4)
{
    int i = blockIdx.x * 256 + threadIdx.x;
    if (i >= n4) return;
    float4 v = reinterpret_cast<const float4*>(x)[i];
    ushort4 h;
    h.x = f2b(v.x); h.y = f2b(v.y); h.z = f2b(v.z); h.w = f2b(v.w);
    reinterpret_cast<ushort4*>(xb)[i] = h;
}

// ------- merged transpose: [Wq | Wkv | Wo] (K x N each, f32) -> Wt rows -------
// Wt is [5120][2048] bf16: rows 0..2047 = Wq^T, 2048..3071 = Wkv^T,
// 3072..5119 = Wo^T. One dispatch, grid (80, 32).
__global__ __launch_bounds__(256) void k_transpose_all(
    const float* __restrict__ Wq, const float* __restrict__ Wkv,
    const float* __restrict__ Wo, unsigned short* __restrict__ Th, int K)
{
    __shared__ float tile[64][65];
    const int n0g = blockIdx.x * 64, k0 = blockIdx.y * 64;
    const float* W; int N, nloc;
    if (n0g < 2048)      { W = Wq;  N = 2048; nloc = n0g; }
    else if (n0g < 3072) { W = Wkv; N = 1024; nloc = n0g - 2048; }
    else                 { W = Wo;  N = 2048; nloc = n0g - 3072; }
    const int c = threadIdx.x & 63, r0 = threadIdx.x >> 6;
    for (int rr = r0; rr < 64; rr += 4)
        tile[rr][c] = W[(size_t)(k0 + rr) * N + nloc + c];
    __syncthreads();
    for (int rr = r0; rr < 64; rr += 4)
        Th[(size_t)(n0g + rr) * K + k0 + c] = f2b(tile[c][rr]);
}

// ------------- plain bf16 GEMM: C = A * B^T(stored [N][K]) -------------
// BK=64, both-sides XOR swizzle (verified r13). Split epilogue.
__global__ __launch_bounds__(256) void k_gemm(
    const unsigned short* __restrict__ A, const unsigned short* __restrict__ B,
    void* __restrict__ CoutA, int NA, void* __restrict__ CoutB, int NB, int N1,
    const float* __restrict__ bias, int M, int K, int outF32)
{
    __shared__ __align__(16) unsigned short As[128][64];
    __shared__ __align__(16) unsigned short Bs[128][64];

    const int tid  = threadIdx.x;
    const int lane = tid & 63, wid = tid >> 6;
    const int wr = wid >> 1, wc = wid & 1;
    const int lrow = lane & 15, lko = (lane >> 4) << 3;
    const int bm = blockIdx.y, bn = blockIdx.x;

    const int srow = tid >> 3;                       // 0..31
    const int scol = ((tid & 7) ^ (srow & 7)) << 3;  // pre-swizzled k-offset
    const int wbase = wid * 1024;

    const int sw = (lrow & 7) << 3;
    const int c0 = lko ^ sw;
    const int c1 = (32 + lko) ^ sw;

    f32x4 acc[4][4] = {};

    const size_t aoff = (size_t)(bm * 128 + srow) * K + scol;
    const size_t boff = (size_t)(bn * 128 + srow) * K + scol;
    const size_t slab = (size_t)32 * K;

    for (int k0 = 0; k0 < K; k0 += 64) {
        #pragma unroll
        for (int s = 0; s < 4; ++s) {
            gload16(&A[aoff + s * slab + k0], (char*)&As[0][0] + s * 4096 + wbase);
            gload16(&B[boff + s * slab + k0], (char*)&Bs[0][0] + s * 4096 + wbase);
        }
        __syncthreads();

        #pragma unroll
        for (int kk2 = 0; kk2 < 2; ++kk2) {
            const int cc = kk2 ? c1 : c0;
            bf16x8 af[4], bf[4];
            #pragma unroll
            for (int m = 0; m < 4; ++m)
                af[m] = *reinterpret_cast<const bf16x8*>(&As[wr * 64 + m * 16 + lrow][cc]);
            #pragma unroll
            for (int n = 0; n < 4; ++n)
                bf[n] = *reinterpret_cast<const bf16x8*>(&Bs[wc * 64 + n * 16 + lrow][cc]);
            #pragma unroll
            for (int m = 0; m < 4; ++m)
                #pragma unroll
                for (int n = 0; n < 4; ++n)
                    acc[m][n] = __builtin_amdgcn_mfma_f32_16x16x32_bf16(af[m], bf[n], acc[m][n], 0, 0, 0);
        }
        __syncthreads();
    }

    const int rbase = bm * 128 + wr * 64 + ((lane >> 4) << 2);
    const int cbase = bn * 128 + wc * 64 + lrow;
    #pragma unroll
    for (int m = 0; m < 4; ++m)
        #pragma unroll
        for (int n = 0; n < 4; ++n) {
            const int col = cbase + n * 16;
            const float bv = bias ? bias[col] : 0.0f;
            const bool inA = (col < N1);
            const int ccol = inA ? col : (col - N1);
            const int cstr = inA ? NA : NB;
            void* base = inA ? CoutA : CoutB;
            #pragma unroll
            for (int r = 0; r < 4; ++r) {
                const size_t idx = (size_t)(rbase + m * 16 + r) * cstr + ccol;
                const float v = acc[m][n][r] + bv;
                if (outF32) ((float*)base)[idx] = v;
                else        ((unsigned short*)base)[idx] = f2b(v);
            }
        }
}

// ------------- fused causal GQA attention with ALiBi -------------
// (verified round-11 version, byte-identical) block = (b, g, 32-row q-chunk),
// 8 waves: waves 0-3 = q-tile q0, waves 4-7 = q-tile q0+16 (same kv head g).
// Shared K/V staging; complementary chunk mapping for CU load balance.
__global__ __launch_bounds__(512, 4) void k_attn(
    const unsigned short* __restrict__ Qb,   // (B*T) x 2048 bf16
    const unsigned short* __restrict__ KVb,  // (B*T) x 1024 bf16 (k | v)
    unsigned short* __restrict__ AO)         // (B*T) x 2048 bf16
{
    __shared__ __align__(16) unsigned short Ksl[64][128]; // [key][dim ^ ((key&7)<<3)]
    __shared__ __align__(16) unsigned short Vt[128][72];  // [dim][key], padded
    __shared__ __align__(16) unsigned short Psl[8][16][72];

    const int blk = blockIdx.x;
    const int idx = blk >> 3;          // 0..63
    const int sub = blk & 7;
    const int b   = sub >> 2;
    const int g   = sub & 3;
    const int chunk = (idx < 32) ? (63 - idx) : (idx - 32);
    const int q0  = chunk * 32;        // 32-row chunk base

    const int tid = threadIdx.x;
    const int lane = tid & 63;
    const int w = tid >> 6;            // wave 0..7
    const int h = (w & 3) * 4 + g;     // query head = rep*KVH + g
    const int q0w = q0 + (w >> 2) * 16;  // this wave's 16-row q-tile
    const float slope = exp2f(-0.5f * (float)(h + 1));
    const float isq = 0.088388347648318447f; // 1/sqrt(128)
    const int lrow = lane & 15;
    const int lko  = (lane >> 4) << 3;
    const int rowg = (lane >> 4) << 2;
    // K staging (512 threads): 2 x uint4 per thread
    const int skey = tid >> 4;                 // 0..31
    const int sd0  = (tid & 15) << 3;          // 0..120
    // V staging (512 threads): 2 key-groups x 8 keys per thread
    const int vdim = tid & 127;                // dim
    const int vkg  = tid >> 7;                 // 0..3

    uint4 kreg[2];                             // in-flight K tile (regs)
    unsigned short vv[2][8];                   // in-flight V tile (regs)

    auto ldK = [&](int kb) {
        const int j0 = kb << 6;
        #pragma unroll
        for (int pp = 0; pp < 2; ++pp) {
            const int key = skey + pp * 32;
            kreg[pp] = *reinterpret_cast<const uint4*>(
                &KVb[(size_t)(b * 2048 + j0 + key) * 1024 + g * 128 + sd0]);
        }
    };
    auto wrK = [&]() {
        #pragma unroll
        for (int pp = 0; pp < 2; ++pp) {
            const int key = skey + pp * 32;
            *reinterpret_cast<uint4*>(&Ksl[key][sd0 ^ ((key & 7) << 3)]) = kreg[pp];
        }
    };
    auto ldV = [&](int kb) {
        const int j0 = kb << 6;
        #pragma unroll
        for (int gi = 0; gi < 2; ++gi) {
            const int kgi = gi * 4 + vkg;
            const size_t base = (size_t)(b * 2048 + j0 + kgi * 8) * 1024 + 512 + g * 128 + vdim;
            #pragma unroll
            for (int j = 0; j < 8; ++j)
                vv[gi][j] = KVb[base + (size_t)j * 1024];
        }
    };
    auto wrV = [&]() {
        #pragma unroll
        for (int gi = 0; gi < 2; ++gi) {
            const int kgi = gi * 4 + vkg;
            *reinterpret_cast<uint4*>(&Vt[vdim][kgi * 8]) =
                *reinterpret_cast<const uint4*>(&vv[gi][0]);
        }
    };

    bf16x8 qf[4];
    {
        const size_t qoff = (size_t)(b * 2048 + q0w + lrow) * 2048 + h * 128 + lko;
        #pragma unroll
        for (int kk = 0; kk < 4; ++kk)
            qf[kk] = *reinterpret_cast<const bf16x8*>(&Qb[qoff + kk * 32]);
    }

    f32x4 oacc[8] = {};
    float mrow = NEG_BIG, lsum = 0.f;
    const int nkb = (q0 + 32 + 63) >> 6;       // block-uniform (covers both tiles)
    const int q = q0w + lrow;                  // this lane's q-row

    // prologue: stage tile 0
    ldK(0); ldV(0);
    wrK(); wrV();
    __syncthreads();

    for (int kb = 0; kb < nkb; ++kb) {
        const int j0 = kb << 6;
        const bool pre = (kb + 1 < nkb);
        if (pre) { ldK(kb + 1); ldV(kb + 1); }

        // S^T = K Q^T : lane owns q-row q, 16 keys in regs
        f32x4 sa[4] = {};
        #pragma unroll
        for (int c = 0; c < 4; ++c) {
            const int krow = c * 16 + lrow;
            #pragma unroll
            for (int kk = 0; kk < 4; ++kk) {
                bf16x8 kf = *reinterpret_cast<const bf16x8*>(
                    &Ksl[krow][(kk * 32 + lko) ^ ((krow & 7) << 3)]);
                sa[c] = __builtin_amdgcn_mfma_f32_16x16x32_bf16(kf, qf[kk], sa[c], 0, 0, 0);
            }
        }

        // in-lane softmax over 16 values (one q-row per lane)
        float pv[4][4];
        float mt = NEG_BIG;
        #pragma unroll
        for (int c = 0; c < 4; ++c)
            #pragma unroll
            for (int r = 0; r < 4; ++r) {
                const int j = j0 + c * 16 + rowg + r;
                const float vsc = (j <= q) ? (sa[c][r] * isq + slope * (float)(j - q)) : NEG_BIG;
                pv[c][r] = vsc;
                mt = fmaxf(mt, vsc);
            }
        mt = fmaxf(mt, __shfl_xor(mt, 16));
        mt = fmaxf(mt, __shfl_xor(mt, 32));
        const float mn = fmaxf(mrow, mt);
        const float alpha = __expf(mrow - mn);
        mrow = mn;
        float s = 0.f;
        #pragma unroll
        for (int c = 0; c < 4; ++c)
            #pragma unroll
            for (int r = 0; r < 4; ++r) {
                const float pe = __expf(pv[c][r] - mn);
                pv[c][r] = pe;
                s += pe;
            }
        s += __shfl_xor(s, 16);
        s += __shfl_xor(s, 32);
        lsum = lsum * alpha + s;

        // redistribute alpha to PV accumulator rows (q = rowg + r)
        float ar[4];
        #pragma unroll
        for (int r = 0; r < 4; ++r) ar[r] = __shfl(alpha, rowg + r);
        #pragma unroll
        for (int f = 0; f < 8; ++f)
            #pragma unroll
            for (int r = 0; r < 4; ++r)
                oacc[f][r] *= ar[r];

        // P pack (cvt_pk) -> per-wave LDS, b64 writes
        #pragma unroll
        for (int c = 0; c < 4; ++c) {
            uint2 pw;
            pw.x = cvtpk(pv[c][0], pv[c][1]);
            pw.y = cvtpk(pv[c][2], pv[c][3]);
            *reinterpret_cast<uint2*>(&Psl[w][lrow][c * 16 + rowg]) = pw;
        }
        asm volatile("s_waitcnt lgkmcnt(0)" ::: "memory");

        #pragma unroll
        for (int kk2 = 0; kk2 < 2; ++kk2) {
            bf16x8 pf = *reinterpret_cast<const bf16x8*>(&Psl[w][lrow][kk2 * 32 + lko]);
            #pragma unroll
            for (int nb = 0; nb < 8; ++nb) {
                bf16x8 vf = *reinterpret_cast<const bf16x8*>(&Vt[nb * 16 + lrow][kk2 * 32 + lko]);
                oacc[nb] = __builtin_amdgcn_mfma_f32_16x16x32_bf16(pf, vf, oacc[nb], 0, 0, 0);
            }
        }

        __syncthreads();             // all waves done reading Ksl/Vt
        if (pre) { wrK(); wrV(); }
        __syncthreads();             // next tile visible
    }

    // epilogue
    float lr[4];
    #pragma unroll
    for (int r = 0; r < 4; ++r) lr[r] = __shfl(lsum, rowg + r);
    #pragma unroll
    for (int nb = 0; nb < 8; ++nb)
        #pragma unroll
        for (int r = 0; r < 4; ++r) {
            const int row = q0w + rowg + r;
            const int col = h * 128 + nb * 16 + lrow;
            const float vo = oacc[nb][r] / lr[r];
            AO[(size_t)(b * 2048 + row) * 2048 + col] = f2b(vo);
        }
}

extern "C" void kernel_launch(void* const* d_in, const int* in_sizes, int n_in,
                              void* d_out, int out_size, void* d_ws, size_t ws_size,
                              hipStream_t stream)
{
    const float* x   = (const float*)d_in[0];  // (2,2048,2048)
    const float* Wq  = (const float*)d_in[1];  // (2048,2048)
    const float* Wkv = (const float*)d_in[2];  // (2048,1024)
    const float* Wo  = (const float*)d_in[3];  // (2048,2048)
    const float* bo  = (const float*)d_in[4];  // (2048,)

    char* ws = (char*)d_ws;
    unsigned short* xb  = (unsigned short*)(ws + (size_t)0);          // 16MB (later AO)
    unsigned short* Wt  = (unsigned short*)(ws + ((size_t)16 << 20)); // 20MB (5120x2048)
    unsigned short* Qb  = (unsigned short*)(ws + ((size_t)36 << 20)); // 16MB
    unsigned short* KVb = (unsigned short*)(ws + ((size_t)52 << 20)); // 8MB
    // total 60MB

    // x -> bf16
    k_convert<<<8192, 256, 0, stream>>>(x, xb, (2 * 2048 * 2048) / 4);

    // all weight transposes in one dispatch:
    // Wt rows 0..2047 = Wq^T, 2048..3071 = Wkv^T, 3072..5119 = Wo^T
    k_transpose_all<<<dim3(80, 32), 256, 0, stream>>>(Wq, Wkv, Wo, Wt, 2048);

    // fused QKV = x @ [Wq | Wkv]  (4096 x 3072 x 2048), split outputs
    k_gemm<<<dim3(24, 32), 256, 0, stream>>>(xb, Wt, Qb, 2048, KVb, 1024, 2048,
                                             nullptr, 4096, 2048, 0);

    // attention -> AO (reuses x buffer)
    k_attn<<<512, 512, 0, stream>>>(Qb, KVb, xb);

    // out = AO @ Wo + bo   (4096 x 2048 x 2048), f32 out
    k_gemm<<<dim3(16, 32), 256, 0, stream>>>(xb, Wt + (size_t)3072 * 2048, d_out, 2048,
                                             nullptr, 2048, 2048, bo, 4096, 2048, 1);
}

// Round 16
// 221.862 us; speedup vs baseline: 1.1456x; 1.0897x over previous
//
#include <hip/hip_runtime.h>

typedef __attribute__((ext_vector_type(8))) __bf16 bf16x8;
typedef __attribute__((ext_vector_type(4))) float f32x4;

#define NEG_BIG (-1e30f)

__device__ __forceinline__ unsigned short f2b(float f) {
    unsigned int u = __float_as_uint(f);
    u += 0x7FFFu + ((u >> 16) & 1u);
    return (unsigned short)(u >> 16);
}
__device__ __forceinline__ unsigned cvtpk(float lo, float hi) {
    unsigned r;
    asm("v_cvt_pk_bf16_f32 %0, %1, %2" : "=v"(r) : "v"(lo), "v"(hi));
    return r;
}

typedef const __attribute__((address_space(1))) unsigned int* gas_ptr;
typedef __attribute__((address_space(3))) unsigned int* las_ptr;
__device__ __forceinline__ void gload16(const void* g, void* l) {
    __builtin_amdgcn_global_load_lds((gas_ptr)g, (las_ptr)l, 16, 0, 0);
}

// ---- merged prep: blocks 0..8191 convert x->bf16; 8192..10751 transpose W ----
// Wt rows: 0..2047 = Wq^T, 2048..3071 = Wkv^T, 3072..5119 = Wo^T (K=2048).
__global__ __launch_bounds__(256) void k_prep(
    const float* __restrict__ x, unsigned short* __restrict__ xb,
    const float* __restrict__ Wq, const float* __restrict__ Wkv,
    const float* __restrict__ Wo, unsigned short* __restrict__ Th)
{
    __shared__ float tile[64][65];
    const int blk = blockIdx.x;
    if (blk < 8192) {
        const int i = blk * 256 + threadIdx.x;   // 8192*256 == (2*2048*2048)/4
        float4 v = reinterpret_cast<const float4*>(x)[i];
        ushort4 h;
        h.x = f2b(v.x); h.y = f2b(v.y); h.z = f2b(v.z); h.w = f2b(v.w);
        reinterpret_cast<ushort4*>(xb)[i] = h;
        return;
    }
    const int bx = blk - 8192;
    const int n0g = (bx % 80) * 64, k0 = (bx / 80) * 64;
    const float* W; int N, nloc;
    if (n0g < 2048)      { W = Wq;  N = 2048; nloc = n0g; }
    else if (n0g < 3072) { W = Wkv; N = 1024; nloc = n0g - 2048; }
    else                 { W = Wo;  N = 2048; nloc = n0g - 3072; }
    const int c = threadIdx.x & 63, r0 = threadIdx.x >> 6;
    for (int rr = r0; rr < 64; rr += 4)
        tile[rr][c] = W[(size_t)(k0 + rr) * N + nloc + c];
    __syncthreads();
    for (int rr = r0; rr < 64; rr += 4)
        Th[(size_t)(n0g + rr) * 2048 + k0 + c] = f2b(tile[c][rr]);
}

// ------------- plain bf16 GEMM: C = A * B^T(stored [N][K]) -------------
// BK=64, both-sides XOR swizzle (verified r13). Split epilogue.
__global__ __launch_bounds__(256) void k_gemm(
    const unsigned short* __restrict__ A, const unsigned short* __restrict__ B,
    void* __restrict__ CoutA, int NA, void* __restrict__ CoutB, int NB, int N1,
    const float* __restrict__ bias, int M, int K, int outF32)
{
    __shared__ __align__(16) unsigned short As[128][64];
    __shared__ __align__(16) unsigned short Bs[128][64];

    const int tid  = threadIdx.x;
    const int lane = tid & 63, wid = tid >> 6;
    const int wr = wid >> 1, wc = wid & 1;
    const int lrow = lane & 15, lko = (lane >> 4) << 3;
    const int bm = blockIdx.y, bn = blockIdx.x;

    const int srow = tid >> 3;                       // 0..31
    const int scol = ((tid & 7) ^ (srow & 7)) << 3;  // pre-swizzled k-offset
    const int wbase = wid * 1024;

    const int sw = (lrow & 7) << 3;
    const int c0 = lko ^ sw;
    const int c1 = (32 + lko) ^ sw;

    f32x4 acc[4][4] = {};

    const size_t aoff = (size_t)(bm * 128 + srow) * K + scol;
    const size_t boff = (size_t)(bn * 128 + srow) * K + scol;
    const size_t slab = (size_t)32 * K;

    for (int k0 = 0; k0 < K; k0 += 64) {
        #pragma unroll
        for (int s = 0; s < 4; ++s) {
            gload16(&A[aoff + s * slab + k0], (char*)&As[0][0] + s * 4096 + wbase);
            gload16(&B[boff + s * slab + k0], (char*)&Bs[0][0] + s * 4096 + wbase);
        }
        __syncthreads();

        #pragma unroll
        for (int kk2 = 0; kk2 < 2; ++kk2) {
            const int cc = kk2 ? c1 : c0;
            bf16x8 af[4], bf[4];
            #pragma unroll
            for (int m = 0; m < 4; ++m)
                af[m] = *reinterpret_cast<const bf16x8*>(&As[wr * 64 + m * 16 + lrow][cc]);
            #pragma unroll
            for (int n = 0; n < 4; ++n)
                bf[n] = *reinterpret_cast<const bf16x8*>(&Bs[wc * 64 + n * 16 + lrow][cc]);
            #pragma unroll
            for (int m = 0; m < 4; ++m)
                #pragma unroll
                for (int n = 0; n < 4; ++n)
                    acc[m][n] = __builtin_amdgcn_mfma_f32_16x16x32_bf16(af[m], bf[n], acc[m][n], 0, 0, 0);
        }
        __syncthreads();
    }

    const int rbase = bm * 128 + wr * 64 + ((lane >> 4) << 2);
    const int cbase = bn * 128 + wc * 64 + lrow;
    #pragma unroll
    for (int m = 0; m < 4; ++m)
        #pragma unroll
        for (int n = 0; n < 4; ++n) {
            const int col = cbase + n * 16;
            const float bv = bias ? bias[col] : 0.0f;
            const bool inA = (col < N1);
            const int ccol = inA ? col : (col - N1);
            const int cstr = inA ? NA : NB;
            void* base = inA ? CoutA : CoutB;
            #pragma unroll
            for (int r = 0; r < 4; ++r) {
                const size_t idx = (size_t)(rbase + m * 16 + r) * cstr + ccol;
                const float v = acc[m][n][r] + bv;
                if (outF32) ((float*)base)[idx] = v;
                else        ((unsigned short*)base)[idx] = f2b(v);
            }
        }
}

// ------------- fused causal GQA attention with ALiBi -------------
// r11-verified skeleton; this round K is staged via global_load_lds DMA
// (double-buffered Ksl, pre-swizzled global source column, linear LDS dest
// -- rule #21; resulting Ksl contents identical to r11's wrK). V unchanged
// (reg-gather-transpose, issue-early/write-late). 8 waves: waves 0-3 =
// q-tile q0, waves 4-7 = q-tile q0+16 (same kv head g).
__global__ __launch_bounds__(512, 4) void k_attn(
    const unsigned short* __restrict__ Qb,   // (B*T) x 2048 bf16
    const unsigned short* __restrict__ KVb,  // (B*T) x 1024 bf16 (k | v)
    unsigned short* __restrict__ AO)         // (B*T) x 2048 bf16
{
    __shared__ __align__(16) unsigned short Ksl[2][64][128]; // [buf][key][dim^((key&7)<<3)]
    __shared__ __align__(16) unsigned short Vt[128][72];     // [dim][key], padded
    __shared__ __align__(16) unsigned short Psl[8][16][72];

    const int blk = blockIdx.x;
    const int idx = blk >> 3;          // 0..63
    const int sub = blk & 7;
    const int b   = sub >> 2;
    const int g   = sub & 3;
    const int chunk = (idx < 32) ? (63 - idx) : (idx - 32);
    const int q0  = chunk * 32;        // 32-row chunk base

    const int tid = threadIdx.x;
    const int lane = tid & 63;
    const int w = tid >> 6;            // wave 0..7
    const int h = (w & 3) * 4 + g;     // query head = rep*KVH + g
    const int q0w = q0 + (w >> 2) * 16;  // this wave's 16-row q-tile
    const float slope = exp2f(-0.5f * (float)(h + 1));
    const float isq = 0.088388347648318447f; // 1/sqrt(128)
    const int lrow = lane & 15;
    const int lko  = (lane >> 4) << 3;
    const int rowg = (lane >> 4) << 2;
    // K DMA staging (512 threads): 2 x gload16 per thread
    const int skey = tid >> 4;                 // 0..31
    const int sd0  = (tid & 15) << 3;          // 0..120
    const int ksrc = sd0 ^ ((skey & 7) << 3);  // pre-swizzled source column
    // V staging (512 threads): 2 key-groups x 8 keys per thread
    const int vdim = tid & 127;                // dim
    const int vkg  = tid >> 7;                 // 0..3

    unsigned short vv[2][8];                   // in-flight V tile (regs)

    auto gloadK = [&](int kb, int buf) {
        const int j0 = kb << 6;
        #pragma unroll
        for (int pp = 0; pp < 2; ++pp) {
            const int key = skey + pp * 32;    // (key&7) == (skey&7)
            gload16(&KVb[(size_t)(b * 2048 + j0 + key) * 1024 + g * 128 + ksrc],
                    (char*)&Ksl[buf][0][0] + pp * 8192 + tid * 16);
        }
    };
    auto ldV = [&](int kb) {
        const int j0 = kb << 6;
        #pragma unroll
        for (int gi = 0; gi < 2; ++gi) {
            const int kgi = gi * 4 + vkg;
            const size_t base = (size_t)(b * 2048 + j0 + kgi * 8) * 1024 + 512 + g * 128 + vdim;
            #pragma unroll
            for (int j = 0; j < 8; ++j)
                vv[gi][j] = KVb[base + (size_t)j * 1024];
        }
    };
    auto wrV = [&]() {
        #pragma unroll
        for (int gi = 0; gi < 2; ++gi) {
            const int kgi = gi * 4 + vkg;
            *reinterpret_cast<uint4*>(&Vt[vdim][kgi * 8]) =
                *reinterpret_cast<const uint4*>(&vv[gi][0]);
        }
    };

    bf16x8 qf[4];
    {
        const size_t qoff = (size_t)(b * 2048 + q0w + lrow) * 2048 + h * 128 + lko;
        #pragma unroll
        for (int kk = 0; kk < 4; ++kk)
            qf[kk] = *reinterpret_cast<const bf16x8*>(&Qb[qoff + kk * 32]);
    }

    f32x4 oacc[8] = {};
    float mrow = NEG_BIG, lsum = 0.f;
    const int nkb = (q0 + 32 + 63) >> 6;       // block-uniform (covers both tiles)
    const int q = q0w + lrow;                  // this lane's q-row

    // prologue: stage tile 0 (K via DMA into buf 0; V via regs)
    gloadK(0, 0);
    ldV(0);
    wrV();
    __syncthreads();                           // drains DMA (vmcnt) + publishes Vt

    int cur = 0;
    for (int kb = 0; kb < nkb; ++kb) {
        const int j0 = kb << 6;
        const bool pre = (kb + 1 < nkb);
        if (pre) { gloadK(kb + 1, cur ^ 1); ldV(kb + 1); }

        // S^T = K Q^T : lane owns q-row q, 16 keys in regs
        f32x4 sa[4] = {};
        #pragma unroll
        for (int c = 0; c < 4; ++c) {
            const int krow = c * 16 + lrow;
            #pragma unroll
            for (int kk = 0; kk < 4; ++kk) {
                bf16x8 kf = *reinterpret_cast<const bf16x8*>(
                    &Ksl[cur][krow][(kk * 32 + lko) ^ ((krow & 7) << 3)]);
                sa[c] = __builtin_amdgcn_mfma_f32_16x16x32_bf16(kf, qf[kk], sa[c], 0, 0, 0);
            }
        }

        // in-lane softmax over 16 values (one q-row per lane)
        float pv[4][4];
        float mt = NEG_BIG;
        #pragma unroll
        for (int c = 0; c < 4; ++c)
            #pragma unroll
            for (int r = 0; r < 4; ++r) {
                const int j = j0 + c * 16 + rowg + r;
                const float vsc = (j <= q) ? (sa[c][r] * isq + slope * (float)(j - q)) : NEG_BIG;
                pv[c][r] = vsc;
                mt = fmaxf(mt, vsc);
            }
        mt = fmaxf(mt, __shfl_xor(mt, 16));
        mt = fmaxf(mt, __shfl_xor(mt, 32));
        const float mn = fmaxf(mrow, mt);
        const float alpha = __expf(mrow - mn);
        mrow = mn;
        float s = 0.f;
        #pragma unroll
        for (int c = 0; c < 4; ++c)
            #pragma unroll
            for (int r = 0; r < 4; ++r) {
                const float pe = __expf(pv[c][r] - mn);
                pv[c][r] = pe;
                s += pe;
            }
        s += __shfl_xor(s, 16);
        s += __shfl_xor(s, 32);
        lsum = lsum * alpha + s;

        // redistribute alpha to PV accumulator rows (q = rowg + r)
        float ar[4];
        #pragma unroll
        for (int r = 0; r < 4; ++r) ar[r] = __shfl(alpha, rowg + r);
        #pragma unroll
        for (int f = 0; f < 8; ++f)
            #pragma unroll
            for (int r = 0; r < 4; ++r)
                oacc[f][r] *= ar[r];

        // P pack (cvt_pk) -> per-wave LDS, b64 writes
        #pragma unroll
        for (int c = 0; c < 4; ++c) {
            uint2 pw;
            pw.x = cvtpk(pv[c][0], pv[c][1]);
            pw.y = cvtpk(pv[c][2], pv[c][3]);
            *reinterpret_cast<uint2*>(&Psl[w][lrow][c * 16 + rowg]) = pw;
        }
        asm volatile("s_waitcnt lgkmcnt(0)" ::: "memory");

        #pragma unroll
        for (int kk2 = 0; kk2 < 2; ++kk2) {
            bf16x8 pf = *reinterpret_cast<const bf16x8*>(&Psl[w][lrow][kk2 * 32 + lko]);
            #pragma unroll
            for (int nb = 0; nb < 8; ++nb) {
                bf16x8 vf = *reinterpret_cast<const bf16x8*>(&Vt[nb * 16 + lrow][kk2 * 32 + lko]);
                oacc[nb] = __builtin_amdgcn_mfma_f32_16x16x32_bf16(pf, vf, oacc[nb], 0, 0, 0);
            }
        }

        __syncthreads();             // all waves done reading Vt/Ksl[cur]
        if (pre) wrV();
        __syncthreads();             // next tile visible (DMA drained too)
        cur ^= 1;
    }

    // epilogue
    float lr[4];
    #pragma unroll
    for (int r = 0; r < 4; ++r) lr[r] = __shfl(lsum, rowg + r);
    #pragma unroll
    for (int nb = 0; nb < 8; ++nb)
        #pragma unroll
        for (int r = 0; r < 4; ++r) {
            const int row = q0w + rowg + r;
            const int col = h * 128 + nb * 16 + lrow;
            const float vo = oacc[nb][r] / lr[r];
            AO[(size_t)(b * 2048 + row) * 2048 + col] = f2b(vo);
        }
}

extern "C" void kernel_launch(void* const* d_in, const int* in_sizes, int n_in,
                              void* d_out, int out_size, void* d_ws, size_t ws_size,
                              hipStream_t stream)
{
    const float* x   = (const float*)d_in[0];  // (2,2048,2048)
    const float* Wq  = (const float*)d_in[1];  // (2048,2048)
    const float* Wkv = (const float*)d_in[2];  // (2048,1024)
    const float* Wo  = (const float*)d_in[3];  // (2048,2048)
    const float* bo  = (const float*)d_in[4];  // (2048,)

    char* ws = (char*)d_ws;
    unsigned short* xb  = (unsigned short*)(ws + (size_t)0);          // 16MB (later AO)
    unsigned short* Wt  = (unsigned short*)(ws + ((size_t)16 << 20)); // 20MB (5120x2048)
    unsigned short* Qb  = (unsigned short*)(ws + ((size_t)36 << 20)); // 16MB
    unsigned short* KVb = (unsigned short*)(ws + ((size_t)52 << 20)); // 8MB
    // total 60MB

    // x -> bf16 AND all weight transposes, one dispatch
    k_prep<<<10752, 256, 0, stream>>>(x, xb, Wq, Wkv, Wo, Wt);

    // fused QKV = x @ [Wq | Wkv]  (4096 x 3072 x 2048), split outputs
    k_gemm<<<dim3(24, 32), 256, 0, stream>>>(xb, Wt, Qb, 2048, KVb, 1024, 2048,
                                             nullptr, 4096, 2048, 0);

    // attention -> AO (reuses x buffer)
    k_attn<<<512, 512, 0, stream>>>(Qb, KVb, xb);

    // out = AO @ Wo + bo   (4096 x 2048 x 2048), f32 out
    k_gemm<<<dim3(16, 32), 256, 0, stream>>>(xb, Wt + (size_t)3072 * 2048, d_out, 2048,
                                             nullptr, 2048, 2048, bo, 4096, 2048, 1);
}